// Round 3
// baseline (1557.098 us; speedup 1.0000x reference)
//
#include <hip/hip_runtime.h>

typedef __attribute__((ext_vector_type(8))) short  short8;
typedef __attribute__((ext_vector_type(4))) float  f32x4;

#define CIN 32
#define COUT 32
#define DD 32
#define HH 48
#define WW 48
#define NTAP 27
#define SPATIAL (DD*HH*WW)          // 73728

// ---- ws layout (bytes) ----
#define OFFS_ELEMS   (81*SPATIAL)                      // offsets, bf16
#define OFF_BP       ((size_t)OFFS_ELEMS*2)            // 11,943,936
#define BP_ELEMS     (32*4*96*8)                       // packed conv weights, bf16
#define OFF_XBF      (OFF_BP + (size_t)BP_ELEMS*2)     // 12,140,544
#define XBF_ELEMS    (CIN*SPATIAL)                     // x in bf16
#define OFF_PART     (OFF_XBF + (size_t)XBF_ELEMS*2)   // 16,859,136 (16B aligned)
#define PART_BYTES   (3ull*COUT*SPATIAL*4)             // 3 f32 partial outputs
#define WS_NEED_PART (OFF_PART + PART_BYTES)           // 45,170,688

__device__ __forceinline__ unsigned short f2bf(float f) {
    union { float f; unsigned u; } v; v.f = f;
    unsigned r = v.u + 0x7FFFu + ((v.u >> 16) & 1u);   // RNE
    return (unsigned short)(r >> 16);
}
__device__ __forceinline__ float bf2f(unsigned short h) {
    union { unsigned u; float f; } v; v.u = ((unsigned)h) << 16;
    return v.f;
}

// ---------------------------------------------------------------- prep kernels
// Bp[c][kg][n][i] = bf16(w_off[n][c][kg*8+i]), zero for n>=81 or tap>=27
__global__ __launch_bounds__(256) void wprep_kernel(
        const float* __restrict__ w_off, unsigned short* __restrict__ Bp)
{
    int i = blockIdx.x * 256 + threadIdx.x;
    if (i >= BP_ELEMS) return;
    int e = i & 7;
    int t = i >> 3;
    int n = t % 96; t /= 96;
    int kg = t & 3;
    int c  = t >> 2;
    int tap = kg * 8 + e;
    float v = 0.f;
    if (n < 81 && tap < 27)
        v = w_off[((size_t)n * CIN + c) * NTAP + tap];
    Bp[i] = f2bf(v);
}

__global__ __launch_bounds__(256) void xprep_kernel(
        const float* __restrict__ x, unsigned short* __restrict__ xb)
{
    int i = blockIdx.x * 256 + threadIdx.x;      // float4 index, 589824 total
    f32x4 v = ((const f32x4*)x)[i];
    ushort4 s;
    s.x = f2bf(v[0]); s.y = f2bf(v[1]); s.z = f2bf(v[2]); s.w = f2bf(v[3]);
    ((ushort4*)xb)[i] = s;
}

__global__ __launch_bounds__(256) void zero_kernel(float* __restrict__ p, int n)
{
    int i = blockIdx.x * 256 + threadIdx.x;
    if (i < n) p[i] = 0.f;
}

// ------------------------------------------- Kernel: offset conv via bf16 MFMA
// Implicit GEMM: D[pos16][oc16] += A[pos16][k32] * B[k32][oc16], K = c*32+tap.
// Block = 4 waves, 64 positions (4x4x4 cube); wave w owns pos w*16..w*16+15.
__global__ __launch_bounds__(256, 4) void conv_mfma(
        const float* __restrict__ x,
        const unsigned short* __restrict__ Bp,
        unsigned short* __restrict__ offs)      // [81][SPATIAL] bf16
{
    __shared__ float xt[CIN * 216];             // [c][6][6][6] halo tile, 27.6 KB

    const int t  = blockIdx.x;                  // 8*12*12 = 1152
    const int d0 = (t / 144) * 4;
    const int h0 = ((t / 12) % 12) * 4;
    const int w0 = (t % 12) * 4;
    const int tid = threadIdx.x;

    for (int i = tid; i < CIN * 216; i += 256) {
        int zw = i % 6, zh = (i / 6) % 6, zd = (i / 36) % 6, c = i / 216;
        int gd = d0 - 1 + zd, gh = h0 - 1 + zh, gw = w0 - 1 + zw;
        float v = 0.f;
        if ((unsigned)gd < DD && (unsigned)gh < HH && (unsigned)gw < WW)
            v = x[(size_t)c * SPATIAL + (gd * HH + gh) * WW + gw];
        xt[i] = v;
    }
    __syncthreads();

    const int lane = tid & 63, wv = tid >> 6;
    const int kg  = lane >> 4;                  // k-group 0..3
    const int col = lane & 15;                  // A: pos row; B/D: oc col
    // A-side position of this lane: pos_local = wv*16 + col
    const int pd = wv, ph = col >> 2, pw = col & 3;

    f32x4 acc[6];
    #pragma unroll
    for (int j = 0; j < 6; ++j) acc[j] = (f32x4){0.f, 0.f, 0.f, 0.f};

    const short8* Bv = (const short8*)Bp;       // one short8 = 8 bf16 = 16 B

    for (int c = 0; c < CIN; ++c) {
        const float* xc = &xt[c * 216];
        short8 af;
        #pragma unroll
        for (int i = 0; i < 8; ++i) {
            int tap = kg * 8 + i;
            int tc  = (tap < 27) ? tap : 0;
            int td = tc / 9, th = (tc / 3) % 3, twk = tc % 3;
            float v = xc[(pd + td) * 36 + (ph + th) * 6 + (pw + twk)];
            af[i] = (tap < 27) ? (short)f2bf(v) : (short)0;
        }
        int bbase = (c * 4 + kg) * 96 + col;
        #pragma unroll
        for (int j = 0; j < 6; ++j) {
            short8 bf = Bv[bbase + j * 16];
            acc[j] = __builtin_amdgcn_mfma_f32_16x16x32_bf16(af, bf, acc[j], 0, 0, 0);
        }
    }

    // D layout: row(pos) = kg*4 + reg, col(oc) = j*16 + col
    // pos_local = wv*16 + kg*4 + reg -> d = d0+wv, h = h0+kg, w = w0+reg
    const int d = d0 + wv, h = h0 + kg;
    #pragma unroll
    for (int j = 0; j < 6; ++j) {
        int oc = j * 16 + col;
        if (oc < 81) {
            ushort4 s;
            s.x = f2bf(acc[j][0]); s.y = f2bf(acc[j][1]);
            s.z = f2bf(acc[j][2]); s.w = f2bf(acc[j][3]);
            *(ushort4*)&offs[(size_t)oc * SPATIAL + (d * HH + h) * WW + w0] = s;
        }
    }
}

// ---------------- Kernel: deformable gather + trilinear + channel contraction
// grid = (288 pos-blocks, 3 tap-groups of 9). ATOMIC=0: write f32 partials.
template<int ATOMIC>
__global__ __launch_bounds__(256, 3) void deform3(
        const unsigned short* __restrict__ xbf,   // [32][SPATIAL] bf16
        const unsigned short* __restrict__ offs,  // [81][SPATIAL] bf16
        const float* __restrict__ w_def,          // [32][32][27]
        float* __restrict__ outp)                 // partials base or out
{
    __shared__ __align__(16) float wt[9 * CIN * COUT];   // 36.9 KB

    const int tid = threadIdx.x;
    const int g   = blockIdx.y;                  // tap group 0..2
    const int pos = blockIdx.x * 256 + tid;
    const int w = pos % WW, h = (pos / WW) % HH, d = pos / (WW * HH);

    for (int j = tid; j < 9 * CIN * COUT; j += 256) {
        int nl = j >> 10, r = j & 1023, c = r >> 5, o = r & 31;
        wt[j] = w_def[((size_t)o * CIN + c) * NTAP + g * 9 + nl];
    }
    __syncthreads();

    const float Dp1 = (float)(DD + 1);
    const float Hp1 = (float)(HH + 1);
    const float Wp1 = (float)(WW + 1);

    float oacc[COUT];
    #pragma unroll
    for (int o = 0; o < COUT; ++o) oacc[o] = 0.f;

    for (int nl = 0; nl < 9; ++nl) {
        const int n = g * 9 + nl;
        float od = bf2f(offs[(size_t)(0 * NTAP + n) * SPATIAL + pos]);
        float oh = bf2f(offs[(size_t)(1 * NTAP + n) * SPATIAL + pos]);
        float ow = bf2f(offs[(size_t)(2 * NTAP + n) * SPATIAL + pos]);
        float rd = (float)(n / 9) - 1.f;
        float rh = (float)((n / 3) % 3) - 1.f;
        float rw = (float)(n % 3) - 1.f;

        float pdp = (float)(d + 1) + rd + od;
        float php = (float)(h + 1) + rh + oh;
        float pwp = (float)(w + 1) + rw + ow;

        float fd = floorf(pdp), fh = floorf(php), fw = floorf(pwp);
        float qd0 = fminf(fmaxf(fd,       0.f), Dp1);
        float qd1 = fminf(fmaxf(fd + 1.f, 0.f), Dp1);
        float qh0 = fminf(fmaxf(fh,       0.f), Hp1);
        float qh1 = fminf(fmaxf(fh + 1.f, 0.f), Hp1);
        float qw0 = fminf(fmaxf(fw,       0.f), Wp1);
        float qw1 = fminf(fmaxf(fw + 1.f, 0.f), Wp1);
        pdp = fminf(fmaxf(pdp, 0.f), Dp1);
        php = fminf(fmaxf(php, 0.f), Hp1);
        pwp = fminf(fmaxf(pwp, 0.f), Wp1);

        float gds[2] = { 1.f + (qd0 - pdp), 1.f - (qd1 - pdp) };
        float ghs[2] = { 1.f + (qh0 - php), 1.f - (qh1 - php) };
        float gws[2] = { 1.f + (qw0 - pwp), 1.f - (qw1 - pwp) };
        int   ids[2] = { (int)qd0, (int)qd1 };
        int   ihs[2] = { (int)qh0, (int)qh1 };
        int   iws[2] = { (int)qw0, (int)qw1 };

        // precompute 8 corner (gain, base, valid)
        float gc[8]; int bs[8]; bool vl[8];
        #pragma unroll
        for (int e = 0; e < 8; ++e) {
            int a = e >> 2, b = (e >> 1) & 1, q = e & 1;
            int zd = ids[a], zh = ihs[b], zw = iws[q];
            gc[e] = gds[a] * ghs[b] * gws[q];
            vl[e] = (zd >= 1) & (zd <= DD) & (zh >= 1) & (zh <= HH)
                  & (zw >= 1) & (zw <= WW);
            bs[e] = vl[e] ? (((zd - 1) * HH + (zh - 1)) * WW + (zw - 1)) : 0;
        }

        float xoff[CIN];
        #pragma unroll
        for (int c = 0; c < CIN; ++c) xoff[c] = 0.f;

        #pragma unroll
        for (int e = 0; e < 8; ++e) {
            float ge = gc[e]; int base = bs[e]; bool val = vl[e];
            #pragma unroll
            for (int c = 0; c < CIN; ++c) {
                float v = val ? bf2f(xbf[(size_t)c * SPATIAL + base]) : 0.f;
                xoff[c] = fmaf(ge, v, xoff[c]);
            }
        }

        const float* wrow = &wt[nl * (CIN * COUT)];
        #pragma unroll 4
        for (int c = 0; c < CIN; ++c) {
            float xv = xoff[c];
            const float4* wr = (const float4*)&wrow[c * COUT];
            #pragma unroll
            for (int o4 = 0; o4 < 8; ++o4) {
                float4 w4 = wr[o4];
                oacc[4*o4+0] = fmaf(xv, w4.x, oacc[4*o4+0]);
                oacc[4*o4+1] = fmaf(xv, w4.y, oacc[4*o4+1]);
                oacc[4*o4+2] = fmaf(xv, w4.z, oacc[4*o4+2]);
                oacc[4*o4+3] = fmaf(xv, w4.w, oacc[4*o4+3]);
            }
        }
    }

    if (ATOMIC) {
        #pragma unroll
        for (int o = 0; o < COUT; ++o)
            atomicAdd(&outp[(size_t)o * SPATIAL + pos], oacc[o]);
    } else {
        float* pg = outp + (size_t)g * COUT * SPATIAL;
        #pragma unroll
        for (int o = 0; o < COUT; ++o)
            pg[(size_t)o * SPATIAL + pos] = oacc[o];
    }
}

__global__ __launch_bounds__(256) void reduce3_kernel(
        const float* __restrict__ part, float* __restrict__ out)
{
    int i = blockIdx.x * 256 + threadIdx.x;      // float4 index, 589824 total
    const f32x4* p0 = (const f32x4*)part;
    const f32x4* p1 = p0 + (COUT * SPATIAL / 4);
    const f32x4* p2 = p1 + (COUT * SPATIAL / 4);
    ((f32x4*)out)[i] = p0[i] + p1[i] + p2[i];
}

// ----------------------------------------------------------------------------
extern "C" void kernel_launch(void* const* d_in, const int* in_sizes, int n_in,
                              void* d_out, int out_size, void* d_ws, size_t ws_size,
                              hipStream_t stream)
{
    const float* x     = (const float*)d_in[0];
    const float* w_off = (const float*)d_in[1];
    const float* w_def = (const float*)d_in[2];
    float* out = (float*)d_out;

    unsigned short* offs = (unsigned short*)((char*)d_ws);
    unsigned short* Bp   = (unsigned short*)((char*)d_ws + OFF_BP);
    unsigned short* xbf  = (unsigned short*)((char*)d_ws + OFF_XBF);
    float*          part = (float*)((char*)d_ws + OFF_PART);

    wprep_kernel<<<(BP_ELEMS + 255) / 256, 256, 0, stream>>>(w_off, Bp);
    xprep_kernel<<<(XBF_ELEMS / 4 + 255) / 256, 256, 0, stream>>>(x, xbf);
    conv_mfma<<<1152, 256, 0, stream>>>(x, Bp, offs);

    if (ws_size >= WS_NEED_PART) {
        deform3<0><<<dim3(288, 3), 256, 0, stream>>>(xbf, offs, w_def, part);
        reduce3_kernel<<<COUT * SPATIAL / 4 / 256, 256, 0, stream>>>(part, out);
    } else {
        int outn = COUT * SPATIAL;
        zero_kernel<<<(outn + 255) / 256, 256, 0, stream>>>(out, outn);
        deform3<1><<<dim3(288, 3), 256, 0, stream>>>(xbf, offs, w_def, out);
    }
}

// Round 4
// 174.116 us; speedup vs baseline: 8.9429x; 8.9429x over previous
//
#include <hip/hip_runtime.h>

typedef __attribute__((ext_vector_type(8))) short  short8;
typedef __attribute__((ext_vector_type(4))) float  f32x4;

#define CIN 32
#define COUT 32
#define DD 32
#define HH 48
#define WW 48
#define NTAP 27
#define SPATIAL (DD*HH*WW)          // 73728

// ---- ws layout (bytes) ----
#define OFF_BP    ((size_t)(81*SPATIAL)*2)           // offs bf16: 11,943,936
#define BP_ELEMS  (32*4*96*8)                        // conv B-pack
#define OFF_WPK   (OFF_BP + (size_t)BP_ELEMS*2)      // 12,140,544
#define WPK_ELEMS (27*2*64*8)                        // einsum B-pack: 27648
#define OFF_XT    (OFF_WPK + (size_t)WPK_ELEMS*2)    // 12,195,840
// xT bf16: 4,718,592 -> total ~16.9 MB (< proven-available 23.9 MB)

__device__ __forceinline__ unsigned short f2bf(float f) {
    union { float f; unsigned u; } v; v.f = f;
    unsigned r = v.u + 0x7FFFu + ((v.u >> 16) & 1u);   // RNE
    return (unsigned short)(r >> 16);
}
__device__ __forceinline__ float bf2f(unsigned short h) {
    union { unsigned u; float f; } v; v.u = ((unsigned)h) << 16;
    return v.f;
}

// ---------------------------------------------------------------- prep kernels
// conv B-pack: Bp[c][kg][n][i] = bf16(w_off[n][c][kg*8+i])
__global__ __launch_bounds__(256) void wprep_kernel(
        const float* __restrict__ w_off, unsigned short* __restrict__ Bp)
{
    int i = blockIdx.x * 256 + threadIdx.x;
    if (i >= BP_ELEMS) return;
    int e = i & 7;
    int t = i >> 3;
    int n = t % 96; t /= 96;
    int kg = t & 3;
    int c  = t >> 2;
    int tap = kg * 8 + e;
    float v = 0.f;
    if (n < 81 && tap < 27)
        v = w_off[((size_t)n * CIN + c) * NTAP + tap];
    Bp[i] = f2bf(v);
}

// einsum B-pack: wpk[((n*2+half)*64+lane)*8+e] = bf16(w_def[half*16+col][kg*8+e][n])
__global__ __launch_bounds__(256) void wdefprep_kernel(
        const float* __restrict__ w_def, unsigned short* __restrict__ wpk)
{
    int i = blockIdx.x * 256 + threadIdx.x;
    if (i >= WPK_ELEMS) return;
    int e    = i & 7;
    int lane = (i >> 3) & 63;
    int half = (i >> 9) & 1;
    int n    = i >> 10;
    int kg = lane >> 4, col = lane & 15;
    int c  = kg * 8 + e, oc = half * 16 + col;
    wpk[i] = f2bf(w_def[((size_t)oc * CIN + c) * NTAP + n]);
}

// x transpose: xT[pos][c] bf16, via LDS tile (coalesced read + 16B stores)
__global__ __launch_bounds__(256) void xtrans_kernel(
        const float* __restrict__ x, unsigned short* __restrict__ xT)
{
    __shared__ float t[CIN][65];
    const int p0 = blockIdx.x * 64;
    const int tid = threadIdx.x;
    const int tx = tid & 63, ty = tid >> 6;
    #pragma unroll
    for (int k = 0; k < 8; ++k) {
        int c = ty + k * 4;
        t[c][tx] = x[(size_t)c * SPATIAL + p0 + tx];
    }
    __syncthreads();
    const int pl = tid >> 2, cg = (tid & 3) * 8;
    short8 v;
    #pragma unroll
    for (int i = 0; i < 8; ++i) v[i] = (short)f2bf(t[cg + i][pl]);
    *(short8*)&xT[((size_t)(p0 + pl)) * 32 + cg] = v;
}

// ------------------------------------------- Kernel: offset conv via bf16 MFMA
__global__ __launch_bounds__(256, 4) void conv_mfma(
        const float* __restrict__ x,
        const unsigned short* __restrict__ Bp,
        unsigned short* __restrict__ offs)      // [81][SPATIAL] bf16
{
    __shared__ float xt[CIN * 216];             // [c][6][6][6] halo tile

    const int t  = blockIdx.x;                  // 1152
    const int d0 = (t / 144) * 4;
    const int h0 = ((t / 12) % 12) * 4;
    const int w0 = (t % 12) * 4;
    const int tid = threadIdx.x;

    for (int i = tid; i < CIN * 216; i += 256) {
        int zw = i % 6, zh = (i / 6) % 6, zd = (i / 36) % 6, c = i / 216;
        int gd = d0 - 1 + zd, gh = h0 - 1 + zh, gw = w0 - 1 + zw;
        float v = 0.f;
        if ((unsigned)gd < DD && (unsigned)gh < HH && (unsigned)gw < WW)
            v = x[(size_t)c * SPATIAL + (gd * HH + gh) * WW + gw];
        xt[i] = v;
    }
    __syncthreads();

    const int lane = tid & 63, wv = tid >> 6;
    const int kg  = lane >> 4;
    const int col = lane & 15;
    const int pd = wv, ph = col >> 2, pw = col & 3;

    f32x4 acc[6];
    #pragma unroll
    for (int j = 0; j < 6; ++j) acc[j] = (f32x4){0.f, 0.f, 0.f, 0.f};

    const short8* Bv = (const short8*)Bp;

    for (int c = 0; c < CIN; ++c) {
        const float* xc = &xt[c * 216];
        short8 af;
        #pragma unroll
        for (int i = 0; i < 8; ++i) {
            int tap = kg * 8 + i;
            int tc  = (tap < 27) ? tap : 0;
            int td = tc / 9, th = (tc / 3) % 3, twk = tc % 3;
            float v = xc[(pd + td) * 36 + (ph + th) * 6 + (pw + twk)];
            af[i] = (tap < 27) ? (short)f2bf(v) : (short)0;
        }
        int bbase = (c * 4 + kg) * 96 + col;
        #pragma unroll
        for (int j = 0; j < 6; ++j) {
            short8 bf = Bv[bbase + j * 16];
            acc[j] = __builtin_amdgcn_mfma_f32_16x16x32_bf16(af, bf, acc[j], 0, 0, 0);
        }
    }

    const int d = d0 + wv, h = h0 + kg;
    #pragma unroll
    for (int j = 0; j < 6; ++j) {
        int oc = j * 16 + col;
        if (oc < 81) {
            ushort4 s;
            s.x = f2bf(acc[j][0]); s.y = f2bf(acc[j][1]);
            s.z = f2bf(acc[j][2]); s.w = f2bf(acc[j][3]);
            *(ushort4*)&offs[(size_t)oc * SPATIAL + (d * HH + h) * WW + w0] = s;
        }
    }
}

// ---------------- Kernel: deform gather + trilinear + MFMA einsum, one pass
// Wave owns 16 consecutive positions. lane = kg*16+row: interp for pos=p0+row,
// channels kg*8..kg*8+7 -> A-frag; two N-halves of w_def -> acc0/acc1.
__global__ __launch_bounds__(256, 4) void deform4(
        const unsigned short* __restrict__ xT,    // [SPATIAL][32] bf16
        const unsigned short* __restrict__ offs,  // [81][SPATIAL] bf16
        const unsigned short* __restrict__ wpk,   // [27][2][64][8] bf16
        float* __restrict__ out)                  // [32][SPATIAL] f32
{
    const int tid  = threadIdx.x;
    const int lane = tid & 63, wv = tid >> 6;
    const int p0   = blockIdx.x * 64 + wv * 16;
    const int kg   = lane >> 4;
    const int row  = lane & 15;
    const int pos  = p0 + row;
    const int w = pos % WW, h = (pos / WW) % HH, d = pos / (WW * HH);

    const float Dp1 = 33.f, Hp1 = 49.f, Wp1 = 49.f;

    f32x4 acc0 = {0.f, 0.f, 0.f, 0.f};
    f32x4 acc1 = {0.f, 0.f, 0.f, 0.f};

    const short8* wv8 = (const short8*)wpk;

    #pragma unroll 1
    for (int n = 0; n < NTAP; ++n) {
        float od = bf2f(offs[(size_t)(0 * NTAP + n) * SPATIAL + pos]);
        float oh = bf2f(offs[(size_t)(1 * NTAP + n) * SPATIAL + pos]);
        float ow = bf2f(offs[(size_t)(2 * NTAP + n) * SPATIAL + pos]);
        float rd = (float)(n / 9) - 1.f;
        float rh = (float)((n / 3) % 3) - 1.f;
        float rw = (float)(n % 3) - 1.f;

        float pdp = (float)(d + 1) + rd + od;
        float php = (float)(h + 1) + rh + oh;
        float pwp = (float)(w + 1) + rw + ow;

        float fd = floorf(pdp), fh = floorf(php), fw = floorf(pwp);
        float qd0 = fminf(fmaxf(fd,       0.f), Dp1);
        float qd1 = fminf(fmaxf(fd + 1.f, 0.f), Dp1);
        float qh0 = fminf(fmaxf(fh,       0.f), Hp1);
        float qh1 = fminf(fmaxf(fh + 1.f, 0.f), Hp1);
        float qw0 = fminf(fmaxf(fw,       0.f), Wp1);
        float qw1 = fminf(fmaxf(fw + 1.f, 0.f), Wp1);
        pdp = fminf(fmaxf(pdp, 0.f), Dp1);
        php = fminf(fmaxf(php, 0.f), Hp1);
        pwp = fminf(fmaxf(pwp, 0.f), Wp1);

        float gds[2] = { 1.f + (qd0 - pdp), 1.f - (qd1 - pdp) };
        float ghs[2] = { 1.f + (qh0 - php), 1.f - (qh1 - php) };
        float gws[2] = { 1.f + (qw0 - pwp), 1.f - (qw1 - pwp) };
        int   ids[2] = { (int)qd0, (int)qd1 };
        int   ihs[2] = { (int)qh0, (int)qh1 };
        int   iws[2] = { (int)qw0, (int)qw1 };

        float xo[8];
        #pragma unroll
        for (int i = 0; i < 8; ++i) xo[i] = 0.f;

        #pragma unroll
        for (int e = 0; e < 8; ++e) {
            int a = e >> 2, b = (e >> 1) & 1, q = e & 1;
            int zd = ids[a], zh = ihs[b], zw = iws[q];
            bool val = (zd >= 1) & (zd <= DD) & (zh >= 1) & (zh <= HH)
                     & (zw >= 1) & (zw <= WW);
            float g  = val ? gds[a] * ghs[b] * gws[q] : 0.f;
            int base = val ? (((zd - 1) * HH + (zh - 1)) * WW + (zw - 1)) : 0;
            short8 v8 = *(const short8*)&xT[(size_t)base * 32 + kg * 8];
            #pragma unroll
            for (int i = 0; i < 8; ++i)
                xo[i] = fmaf(g, bf2f((unsigned short)v8[i]), xo[i]);
        }

        // hi/lo bf16 split of xoff for near-f32 MFMA accuracy
        short8 ahi, alo;
        #pragma unroll
        for (int i = 0; i < 8; ++i) {
            unsigned short hb = f2bf(xo[i]);
            ahi[i] = (short)hb;
            alo[i] = (short)f2bf(xo[i] - bf2f(hb));
        }

        short8 b0 = wv8[(n * 2 + 0) * 64 + lane];
        short8 b1 = wv8[(n * 2 + 1) * 64 + lane];
        acc0 = __builtin_amdgcn_mfma_f32_16x16x32_bf16(ahi, b0, acc0, 0, 0, 0);
        acc0 = __builtin_amdgcn_mfma_f32_16x16x32_bf16(alo, b0, acc0, 0, 0, 0);
        acc1 = __builtin_amdgcn_mfma_f32_16x16x32_bf16(ahi, b1, acc1, 0, 0, 0);
        acc1 = __builtin_amdgcn_mfma_f32_16x16x32_bf16(alo, b1, acc1, 0, 0, 0);
    }

    // D layout: col = lane&15 -> oc, row = kg*4+reg -> pos
    const int oc0 = row, oc1 = 16 + row;
    const int pb  = p0 + kg * 4;
    *(f32x4*)&out[(size_t)oc0 * SPATIAL + pb] = acc0;
    *(f32x4*)&out[(size_t)oc1 * SPATIAL + pb] = acc1;
}

// ----------------------------------------------------------------------------
extern "C" void kernel_launch(void* const* d_in, const int* in_sizes, int n_in,
                              void* d_out, int out_size, void* d_ws, size_t ws_size,
                              hipStream_t stream)
{
    const float* x     = (const float*)d_in[0];
    const float* w_off = (const float*)d_in[1];
    const float* w_def = (const float*)d_in[2];
    float* out = (float*)d_out;

    unsigned short* offs = (unsigned short*)((char*)d_ws);
    unsigned short* Bp   = (unsigned short*)((char*)d_ws + OFF_BP);
    unsigned short* wpk  = (unsigned short*)((char*)d_ws + OFF_WPK);
    unsigned short* xT   = (unsigned short*)((char*)d_ws + OFF_XT);

    wprep_kernel<<<(BP_ELEMS + 255) / 256, 256, 0, stream>>>(w_off, Bp);
    wdefprep_kernel<<<(WPK_ELEMS + 255) / 256, 256, 0, stream>>>(w_def, wpk);
    xtrans_kernel<<<SPATIAL / 64, 256, 0, stream>>>(x, xT);
    conv_mfma<<<1152, 256, 0, stream>>>(x, Bp, offs);
    deform4<<<SPATIAL / 64, 256, 0, stream>>>(xT, offs, wpk, out);
}

// Round 5
// 137.083 us; speedup vs baseline: 11.3588x; 1.2702x over previous
//
#include <hip/hip_runtime.h>

typedef __attribute__((ext_vector_type(8))) short  short8;
typedef __attribute__((ext_vector_type(4))) float  f32x4;

#define CIN 32
#define COUT 32
#define DD 32
#define HH 48
#define WW 48
#define NTAP 27
#define SPATIAL (DD*HH*WW)          // 73728

// ---- ws layout (bytes) ----
#define BP2_ELEMS (27*6*64*8)                       // conv B-pack: 82944
#define OFF_WPK   ((size_t)BP2_ELEMS*2)             // 165888
#define WPK_ELEMS (27*2*64*8)                       // einsum B-pack: 27648
#define OFF_XT    (OFF_WPK + (size_t)WPK_ELEMS*2)   // 221184 (16B aligned)
// xT bf16: 4,718,592 B -> total ~4.94 MB

__device__ __forceinline__ unsigned short f2bf(float f) {
    union { float f; unsigned u; } v; v.f = f;
    unsigned r = v.u + 0x7FFFu + ((v.u >> 16) & 1u);   // RNE
    return (unsigned short)(r >> 16);
}
__device__ __forceinline__ float bf2f(unsigned short h) {
    union { unsigned u; float f; } v; v.u = ((unsigned)h) << 16;
    return v.f;
}

// ---------------------------------------------------------------- prep kernels
// conv B-pack for tap-major K: Bp2[((n*6+j)*64+lane)*8+e] =
//   bf16(w_off[j*16+col][kg*8+e][n]), 0 for oc>=81. lane=(kg<<4)|col.
__global__ __launch_bounds__(256) void wprep2_kernel(
        const float* __restrict__ w_off, unsigned short* __restrict__ Bp2)
{
    int i = blockIdx.x * 256 + threadIdx.x;
    if (i >= BP2_ELEMS) return;
    int e    = i & 7;
    int lane = (i >> 3) & 63;
    int j    = (i >> 9) % 6;
    int n    = i / (512 * 6);
    int col = lane & 15, kg = lane >> 4;
    int oc = j * 16 + col, c = kg * 8 + e;
    float v = (oc < 81) ? w_off[((size_t)oc * CIN + c) * NTAP + n] : 0.f;
    Bp2[i] = f2bf(v);
}

// einsum B-pack: wpk[((n*2+half)*64+lane)*8+e] = bf16(w_def[half*16+col][kg*8+e][n])
__global__ __launch_bounds__(256) void wdefprep_kernel(
        const float* __restrict__ w_def, unsigned short* __restrict__ wpk)
{
    int i = blockIdx.x * 256 + threadIdx.x;
    if (i >= WPK_ELEMS) return;
    int e    = i & 7;
    int lane = (i >> 3) & 63;
    int half = (i >> 9) & 1;
    int n    = i >> 10;
    int kg = lane >> 4, col = lane & 15;
    int c  = kg * 8 + e, oc = half * 16 + col;
    wpk[i] = f2bf(w_def[((size_t)oc * CIN + c) * NTAP + n]);
}

// x transpose: xT[pos][c] bf16 (coalesced read via LDS, 16B stores)
__global__ __launch_bounds__(256) void xtrans_kernel(
        const float* __restrict__ x, unsigned short* __restrict__ xT)
{
    __shared__ float t[CIN][65];
    const int p0 = blockIdx.x * 64;
    const int tid = threadIdx.x;
    const int tx = tid & 63, ty = tid >> 6;
    #pragma unroll
    for (int k = 0; k < 8; ++k) {
        int c = ty + k * 4;
        t[c][tx] = x[(size_t)c * SPATIAL + p0 + tx];
    }
    __syncthreads();
    const int pl = tid >> 2, cg = (tid & 3) * 8;
    short8 v;
    #pragma unroll
    for (int i = 0; i < 8; ++i) v[i] = (short)f2bf(t[cg + i][pl]);
    *(short8*)&xT[((size_t)(p0 + pl)) * 32 + cg] = v;
}

// ---------------- Fused kernel: offset conv (MFMA) -> LDS -> deform (MFMA)
// Wave owns 16 consecutive positions. lane = kg*16+row.
// Phase 1: implicit-GEMM conv, K-step = one tap's 32 channels, A from xT.
// Phase 2: D-fragments -> LDS [pos16][97] f32 per wave.
// Phase 3: trilinear gather + hi/lo bf16 MFMA einsum, direct f32x4 stores.
__global__ __launch_bounds__(256, 4) void fused_deform(
        const unsigned short* __restrict__ xT,    // [SPATIAL][32] bf16
        const unsigned short* __restrict__ Bp2,   // conv B-pack
        const unsigned short* __restrict__ wpk,   // einsum B-pack
        float* __restrict__ out)                  // [32][SPATIAL] f32
{
    __shared__ float offl[4][16][97];             // 24.8 KB

    const int tid  = threadIdx.x;
    const int lane = tid & 63, wv = tid >> 6;
    const int p0   = blockIdx.x * 64 + wv * 16;
    const int kg   = lane >> 4;
    const int row  = lane & 15;
    const int pos  = p0 + row;
    const int w = pos % WW, h = (pos / WW) % HH, d = pos / (WW * HH);

    // ---------------- phase 1: offset conv ----------------
    f32x4 cacc[6];
    #pragma unroll
    for (int j = 0; j < 6; ++j) cacc[j] = (f32x4){0.f, 0.f, 0.f, 0.f};

    const short8* Bv = (const short8*)Bp2;
    {
        int n = 0;
        #pragma unroll 1
        for (int td = -1; td <= 1; ++td) {
            #pragma unroll 1
            for (int th = -1; th <= 1; ++th) {
                #pragma unroll
                for (int tw = -1; tw <= 1; ++tw, ++n) {
                    bool valid = ((unsigned)(d + td) < DD)
                               & ((unsigned)(h + th) < HH)
                               & ((unsigned)(w + tw) < WW);
                    int dpos = pos + (td * HH + th) * WW + tw;
                    short8 af = {0, 0, 0, 0, 0, 0, 0, 0};
                    if (valid)
                        af = *(const short8*)&xT[dpos * 32 + kg * 8];
                    #pragma unroll
                    for (int j = 0; j < 6; ++j)
                        cacc[j] = __builtin_amdgcn_mfma_f32_16x16x32_bf16(
                                      af, Bv[(n * 6 + j) * 64 + lane], cacc[j], 0, 0, 0);
                }
            }
        }
    }

    // ---------------- phase 2: D-fragments -> LDS ----------------
    // D: row(pos_local) = kg*4+r, col(oc) = j*16+row
    #pragma unroll
    for (int j = 0; j < 6; ++j) {
        #pragma unroll
        for (int r = 0; r < 4; ++r)
            offl[wv][kg * 4 + r][j * 16 + row] = cacc[j][r];
    }
    __syncthreads();

    // ---------------- phase 3: deform gather + einsum ----------------
    const float Dp1 = 33.f, Hp1 = 49.f, Wp1 = 49.f;
    const float* ol = &offl[wv][row][0];

    f32x4 acc0 = {0.f, 0.f, 0.f, 0.f};
    f32x4 acc1 = {0.f, 0.f, 0.f, 0.f};
    const short8* wv8 = (const short8*)wpk;

    #pragma unroll 1
    for (int n = 0; n < NTAP; ++n) {
        float od = ol[n];
        float oh = ol[27 + n];
        float ow = ol[54 + n];
        float rd = (float)(n / 9) - 1.f;
        float rh = (float)((n / 3) % 3) - 1.f;
        float rw = (float)(n % 3) - 1.f;

        float pdp = (float)(d + 1) + rd + od;
        float php = (float)(h + 1) + rh + oh;
        float pwp = (float)(w + 1) + rw + ow;

        float fd = floorf(pdp), fh = floorf(php), fw = floorf(pwp);
        float qd0 = fminf(fmaxf(fd,       0.f), Dp1);
        float qd1 = fminf(fmaxf(fd + 1.f, 0.f), Dp1);
        float qh0 = fminf(fmaxf(fh,       0.f), Hp1);
        float qh1 = fminf(fmaxf(fh + 1.f, 0.f), Hp1);
        float qw0 = fminf(fmaxf(fw,       0.f), Wp1);
        float qw1 = fminf(fmaxf(fw + 1.f, 0.f), Wp1);
        pdp = fminf(fmaxf(pdp, 0.f), Dp1);
        php = fminf(fmaxf(php, 0.f), Hp1);
        pwp = fminf(fmaxf(pwp, 0.f), Wp1);

        float gds[2] = { 1.f + (qd0 - pdp), 1.f - (qd1 - pdp) };
        float ghs[2] = { 1.f + (qh0 - php), 1.f - (qh1 - php) };
        float gws[2] = { 1.f + (qw0 - pwp), 1.f - (qw1 - pwp) };
        int   ids[2] = { (int)qd0, (int)qd1 };
        int   ihs[2] = { (int)qh0, (int)qh1 };
        int   iws[2] = { (int)qw0, (int)qw1 };

        float xo[8];
        #pragma unroll
        for (int i = 0; i < 8; ++i) xo[i] = 0.f;

        #pragma unroll
        for (int e = 0; e < 8; ++e) {
            int a = e >> 2, b = (e >> 1) & 1, q = e & 1;
            int zd = ids[a], zh = ihs[b], zw = iws[q];
            bool val = (zd >= 1) & (zd <= DD) & (zh >= 1) & (zh <= HH)
                     & (zw >= 1) & (zw <= WW);
            float g  = val ? gds[a] * ghs[b] * gws[q] : 0.f;
            int base = val ? (((zd - 1) * HH + (zh - 1)) * WW + (zw - 1)) : 0;
            short8 v8 = *(const short8*)&xT[base * 32 + kg * 8];
            #pragma unroll
            for (int i = 0; i < 8; ++i)
                xo[i] = fmaf(g, bf2f((unsigned short)v8[i]), xo[i]);
        }

        // hi/lo bf16 split of xoff for near-f32 MFMA accuracy
        short8 ahi, alo;
        #pragma unroll
        for (int i = 0; i < 8; ++i) {
            unsigned short hb = f2bf(xo[i]);
            ahi[i] = (short)hb;
            alo[i] = (short)f2bf(xo[i] - bf2f(hb));
        }

        short8 b0 = wv8[(n * 2 + 0) * 64 + lane];
        short8 b1 = wv8[(n * 2 + 1) * 64 + lane];
        acc0 = __builtin_amdgcn_mfma_f32_16x16x32_bf16(ahi, b0, acc0, 0, 0, 0);
        acc0 = __builtin_amdgcn_mfma_f32_16x16x32_bf16(alo, b0, acc0, 0, 0, 0);
        acc1 = __builtin_amdgcn_mfma_f32_16x16x32_bf16(ahi, b1, acc1, 0, 0, 0);
        acc1 = __builtin_amdgcn_mfma_f32_16x16x32_bf16(alo, b1, acc1, 0, 0, 0);
    }

    // D layout: col = lane&15 -> oc, row = kg*4+reg -> pos
    const int oc0 = row, oc1 = 16 + row;
    const int pb  = p0 + kg * 4;
    *(f32x4*)&out[(size_t)oc0 * SPATIAL + pb] = acc0;
    *(f32x4*)&out[(size_t)oc1 * SPATIAL + pb] = acc1;
}

// ----------------------------------------------------------------------------
extern "C" void kernel_launch(void* const* d_in, const int* in_sizes, int n_in,
                              void* d_out, int out_size, void* d_ws, size_t ws_size,
                              hipStream_t stream)
{
    const float* x     = (const float*)d_in[0];
    const float* w_off = (const float*)d_in[1];
    const float* w_def = (const float*)d_in[2];
    float* out = (float*)d_out;

    unsigned short* Bp2 = (unsigned short*)((char*)d_ws);
    unsigned short* wpk = (unsigned short*)((char*)d_ws + OFF_WPK);
    unsigned short* xT  = (unsigned short*)((char*)d_ws + OFF_XT);

    wprep2_kernel<<<(BP2_ELEMS + 255) / 256, 256, 0, stream>>>(w_off, Bp2);
    wdefprep_kernel<<<(WPK_ELEMS + 255) / 256, 256, 0, stream>>>(w_def, wpk);
    xtrans_kernel<<<SPATIAL / 64, 256, 0, stream>>>(x, xT);
    fused_deform<<<SPATIAL / 64, 256, 0, stream>>>(xT, Bp2, wpk, out);
}